// Round 1
// baseline (1574.463 us; speedup 1.0000x reference)
//
#include <hip/hip_runtime.h>

#define N_NODES 100000
#define N_EDGES 1600000
#define N_GRAPHS 128
#define FDIM 64
#define EPSV 1e-5f
#define NEG 0.01f

__device__ __forceinline__ float leaky(float x){ return x >= 0.f ? x : NEG*x; }

// ---------------- degree (shared by both layers) ----------------
__global__ void k_deg(const int* __restrict__ dst, float* __restrict__ deg){
    int e = blockIdx.x*256 + threadIdx.x;
    if (e < N_EDGES) atomicAdd(&deg[dst[e]], 1.0f);
}

// ---------------- edge scatter: agg[dst] += affine(x[src]) ----------------
template<bool AFFINE>
__global__ void k_scatter(const int* __restrict__ src, const int* __restrict__ dst,
                          const float* __restrict__ x, float* __restrict__ agg,
                          const float* __restrict__ scale, const float* __restrict__ shift){
    long long t = (long long)blockIdx.x*256 + threadIdx.x;
    int e = (int)(t >> 6);
    int j = (int)(t & 63);
    if (e < N_EDGES){
        float v = x[(long long)src[e]*FDIM + j];
        if (AFFINE) v = v*scale[j] + shift[j];
        atomicAdd(&agg[(long long)dst[e]*FDIM + j], v);
    }
}

// ---------------- fused: h = leaky((agg/deg)@Wl + bl + affine(xin)@Wr), in-place over agg,
//                  accumulates BN sum / sumsq ----------------
template<bool AFFINE>
__global__ __launch_bounds__(256) void k_h(
    float* __restrict__ agg, const float* __restrict__ xin,
    const float* __restrict__ Wl, const float* __restrict__ bl,
    const float* __restrict__ Wr,
    const float* __restrict__ deg,
    float* __restrict__ bnsum, float* __restrict__ bnsq,
    const float* __restrict__ scale, const float* __restrict__ shift)
{
    __shared__ float sWl[FDIM*FDIM];
    __shared__ float sWr[FDIM*FDIM];
    __shared__ float rowA[4][FDIM];
    __shared__ float rowX[4][FDIM];
    __shared__ float red[256];

    int t = threadIdx.x;
    for (int i = t; i < FDIM*FDIM; i += 256){ sWl[i] = Wl[i]; sWr[i] = Wr[i]; }
    int j = t & 63, slot = t >> 6;
    float blj = bl[j];
    float scj = AFFINE ? scale[j] : 1.f;
    float shj = AFFINE ? shift[j] : 0.f;
    float bsum = 0.f, bsq = 0.f;
    __syncthreads();

    const int nchunk = N_NODES/4;   // 25000, exact
    for (int c = blockIdx.x; c < nchunk; c += gridDim.x){
        int n = c*4 + slot;
        float rd = 1.f / fmaxf(deg[n], 1.f);
        rowA[slot][j] = agg[n*FDIM + j] * rd;
        float xv = xin[n*FDIM + j];
        rowX[slot][j] = AFFINE ? (xv*scj + shj) : xv;
        __syncthreads();
        float acc = blj;
        #pragma unroll 8
        for (int k = 0; k < FDIM; ++k)
            acc += rowA[slot][k]*sWl[k*FDIM + j] + rowX[slot][k]*sWr[k*FDIM + j];
        float h = leaky(acc);
        agg[n*FDIM + j] = h;          // in-place: agg row already staged in LDS
        bsum += h; bsq += h*h;
        __syncthreads();
    }

    red[t] = bsum; __syncthreads();
    if (t < 64) atomicAdd(&bnsum[t], red[t]+red[t+64]+red[t+128]+red[t+192]);
    __syncthreads();
    red[t] = bsq; __syncthreads();
    if (t < 64) atomicAdd(&bnsq[t],  red[t]+red[t+64]+red[t+128]+red[t+192]);
}

// ---------------- BN finalize: fold mean/var/gamma/beta into scale/shift ----------------
__global__ void k_bnfin(const float* __restrict__ sum, const float* __restrict__ sumsq,
                        const float* __restrict__ gamma, const float* __restrict__ beta,
                        float* __restrict__ scale, float* __restrict__ shift){
    int j = threadIdx.x;
    if (j < FDIM){
        float mu  = sum[j]   * (1.0f/N_NODES);
        float var = sumsq[j] * (1.0f/N_NODES) - mu*mu;
        float sc  = gamma[j] * rsqrtf(var + EPSV);
        scale[j] = sc;
        shift[j] = beta[j] - mu*sc;
    }
}

// ---------------- pooling: pooled[batch[n]] += affine(h[n]); cnt[batch[n]]++ ----------------
__global__ void k_pool(const float* __restrict__ h, const int* __restrict__ batch,
                       const float* __restrict__ scale, const float* __restrict__ shift,
                       float* __restrict__ pooled, float* __restrict__ cnt){
    long long t = (long long)blockIdx.x*256 + threadIdx.x;
    int n = (int)(t >> 6), j = (int)(t & 63);
    if (n < N_NODES){
        int g = batch[n];
        float v = h[(long long)n*FDIM + j]*scale[j] + shift[j];
        atomicAdd(&pooled[g*FDIM + j], v);
        if (j == 0) atomicAdd(&cnt[g], 1.f);
    }
}

// ---------------- final MLP: one block per graph ----------------
__global__ __launch_bounds__(256) void k_mlp(
    const float* __restrict__ pooled, const float* __restrict__ cnt,
    const float* __restrict__ gf,
    const float* __restrict__ Wm0, const float* __restrict__ bm0,
    const float* __restrict__ Wm1, const float* __restrict__ bm1,
    const float* __restrict__ Wm2, const float* __restrict__ bm2,
    float* __restrict__ out)
{
    __shared__ float z[128];
    __shared__ float h1[256];
    __shared__ float h2[128];
    int g = blockIdx.x, t = threadIdx.x;
    if (t < 64)       z[t] = pooled[g*FDIM + t] / fmaxf(cnt[g], 1.f);
    else if (t < 128) z[t] = gf[g*FDIM + (t-64)];
    __syncthreads();
    float acc = bm0[t];
    #pragma unroll 8
    for (int k = 0; k < 128; ++k) acc += z[k]*Wm0[k*256 + t];
    h1[t] = leaky(acc);
    __syncthreads();
    if (t < 128){
        float a = bm1[t];
        #pragma unroll 8
        for (int k = 0; k < 256; ++k) a += h1[k]*Wm1[k*128 + t];
        h2[t] = leaky(a);
    }
    __syncthreads();
    if (t < 2){
        float a = bm2[t];
        for (int k = 0; k < 128; ++k) a += h2[k]*Wm2[k*2 + t];
        out[g*2 + t] = a;
    }
}

extern "C" void kernel_launch(void* const* d_in, const int* in_sizes, int n_in,
                              void* d_out, int out_size, void* d_ws, size_t ws_size,
                              hipStream_t stream) {
    const float* x     = (const float*)d_in[0];
    const int*   ei    = (const int*)d_in[1];      // [2, E]: src row then dst row
    const float* gf    = (const float*)d_in[2];
    const int*   batch = (const int*)d_in[3];
    const float* Wl0 = (const float*)d_in[4];
    const float* bl0 = (const float*)d_in[5];
    const float* Wr0 = (const float*)d_in[6];
    const float* g0  = (const float*)d_in[7];
    const float* b0  = (const float*)d_in[8];
    const float* Wl1 = (const float*)d_in[9];
    const float* bl1 = (const float*)d_in[10];
    const float* Wr1 = (const float*)d_in[11];
    const float* g1  = (const float*)d_in[12];
    const float* b1  = (const float*)d_in[13];
    const float* Wm0 = (const float*)d_in[14];
    const float* bm0 = (const float*)d_in[15];
    const float* Wm1 = (const float*)d_in[16];
    const float* bm1 = (const float*)d_in[17];
    const float* Wm2 = (const float*)d_in[18];
    const float* bm2 = (const float*)d_in[19];

    float* ws     = (float*)d_ws;
    float* bufA   = ws;                       // [N,64] agg1 -> h1
    float* bufB   = ws + 6400000;             // [N,64] agg2 -> h2
    float* deg    = ws + 12800000;            // [N]
    float* bnsum  = ws + 12900000;            // [64]
    float* bnsq   = bnsum + 64;               // [64]
    float* scale0 = bnsum + 128;
    float* shift0 = bnsum + 192;
    float* scale1 = bnsum + 256;
    float* shift1 = bnsum + 320;
    float* pooled = bnsum + 384;              // [128,64]
    float* cnt    = pooled + N_GRAPHS*FDIM;   // [128]

    const int* srcp = ei;
    const int* dstp = ei + N_EDGES;

    hipMemsetAsync(bufA, 0, (size_t)N_NODES*FDIM*sizeof(float), stream);
    // deg + bn accumulators + scale/shift + pooled + cnt are contiguous
    hipMemsetAsync(deg, 0, (size_t)(N_NODES + 384 + N_GRAPHS*FDIM + N_GRAPHS)*sizeof(float), stream);

    k_deg<<<(N_EDGES+255)/256, 256, 0, stream>>>(dstp, deg);

    const int sc_blocks = (int)(((long long)N_EDGES*64 + 255)/256);   // 400000
    k_scatter<false><<<sc_blocks, 256, 0, stream>>>(srcp, dstp, x, bufA, nullptr, nullptr);
    k_h<false><<<1024, 256, 0, stream>>>(bufA, x, Wl0, bl0, Wr0, deg, bnsum, bnsq, nullptr, nullptr);
    k_bnfin<<<1, 64, 0, stream>>>(bnsum, bnsq, g0, b0, scale0, shift0);

    hipMemsetAsync(bufB, 0, (size_t)N_NODES*FDIM*sizeof(float), stream);
    hipMemsetAsync(bnsum, 0, 128*sizeof(float), stream);

    k_scatter<true><<<sc_blocks, 256, 0, stream>>>(srcp, dstp, bufA, bufB, scale0, shift0);
    k_h<true><<<1024, 256, 0, stream>>>(bufB, bufA, Wl1, bl1, Wr1, deg, bnsum, bnsq, scale0, shift0);
    k_bnfin<<<1, 64, 0, stream>>>(bnsum, bnsq, g1, b1, scale1, shift1);

    k_pool<<<(int)(((long long)N_NODES*64 + 255)/256), 256, 0, stream>>>(bufB, batch, scale1, shift1, pooled, cnt);

    k_mlp<<<N_GRAPHS, 256, 0, stream>>>(pooled, cnt, gf, Wm0, bm0, Wm1, bm1, Wm2, bm2, (float*)d_out);
}

// Round 2
// 646.372 us; speedup vs baseline: 2.4358x; 2.4358x over previous
//
#include <hip/hip_runtime.h>

#define N_NODES 100000
#define N_EDGES 1600000
#define N_GRAPHS 128
#define FDIM 64
#define EPSV 1e-5f
#define NEG 0.01f

__device__ __forceinline__ float leaky(float x){ return x >= 0.f ? x : NEG*x; }

// ================= CSR build =================
__global__ void k_hist(const int* __restrict__ dst, int* __restrict__ cnts){
    int e = blockIdx.x*256 + threadIdx.x;
    if (e < N_EDGES) atomicAdd(&cnts[dst[e]], 1);
}

// block scans 1024 counts (256 thr x 4), writes per-element exclusive scan + block total
__global__ __launch_bounds__(256) void k_scanA(const int* __restrict__ cnts,
                                               int* __restrict__ rs, int* __restrict__ bsum){
    __shared__ int lds[256];
    int b = blockIdx.x, t = threadIdx.x;
    int base = b*1024 + t*4;
    int v0=0,v1=0,v2=0,v3=0;
    if (base+0 < N_NODES) v0 = cnts[base+0];
    if (base+1 < N_NODES) v1 = cnts[base+1];
    if (base+2 < N_NODES) v2 = cnts[base+2];
    if (base+3 < N_NODES) v3 = cnts[base+3];
    lds[t] = v0+v1+v2+v3; __syncthreads();
    for (int off=1; off<256; off<<=1){
        int add = (t>=off) ? lds[t-off] : 0; __syncthreads();
        lds[t] += add; __syncthreads();
    }
    int excl = (t>0) ? lds[t-1] : 0;
    if (base+0 < N_NODES) rs[base+0] = excl;
    if (base+1 < N_NODES) rs[base+1] = excl+v0;
    if (base+2 < N_NODES) rs[base+2] = excl+v0+v1;
    if (base+3 < N_NODES) rs[base+3] = excl+v0+v1+v2;
    if (t == 255) bsum[b] = lds[255];
}

__global__ void k_scanB(int* __restrict__ bsum, int nblk){
    __shared__ int lds[128];
    int t = threadIdx.x;
    lds[t] = (t < nblk) ? bsum[t] : 0; __syncthreads();
    for (int off=1; off<128; off<<=1){
        int add = (t>=off) ? lds[t-off] : 0; __syncthreads();
        lds[t] += add; __syncthreads();
    }
    if (t < nblk) bsum[t] = (t>0) ? lds[t-1] : 0;   // exclusive block offsets
}

__global__ void k_scanC(int* __restrict__ rs, const int* __restrict__ bsum, int* __restrict__ cur){
    int i = blockIdx.x*256 + threadIdx.x;
    if (i < N_NODES){
        int v = rs[i] + bsum[i>>10];
        rs[i] = v; cur[i] = v;
    }
    if (i == 0) rs[N_NODES] = N_EDGES;
}

__global__ void k_fill(const int* __restrict__ src, const int* __restrict__ dst,
                       int* __restrict__ cur, int* __restrict__ col){
    int e = blockIdx.x*256 + threadIdx.x;
    if (e < N_EDGES){
        int p = atomicAdd(&cur[dst[e]], 1);
        col[p] = src[e];
    }
}

// ============ fused gather-mean + dual GEMM + leaky + BN partials ============
template<bool AFFINE>
__global__ __launch_bounds__(256) void k_hg(
    const float* __restrict__ xin, const int* __restrict__ rs, const int* __restrict__ col,
    const float* __restrict__ Wl, const float* __restrict__ bl, const float* __restrict__ Wr,
    float* __restrict__ hout,
    float* __restrict__ bnsum, float* __restrict__ bnsq,
    const float* __restrict__ scale, const float* __restrict__ shift)
{
    __shared__ float sWl[FDIM*FDIM];
    __shared__ float sWr[FDIM*FDIM];
    __shared__ float rowA[4][FDIM];
    __shared__ float rowX[4][FDIM];
    __shared__ float red[256];

    int t = threadIdx.x;
    for (int i = t; i < FDIM*FDIM; i += 256){ sWl[i] = Wl[i]; sWr[i] = Wr[i]; }
    int j = t & 63, slot = t >> 6;           // slot == wave id
    float blj = bl[j];
    float scj = AFFINE ? scale[j] : 1.f;
    float shj = AFFINE ? shift[j] : 0.f;
    float bsumv = 0.f, bsqv = 0.f;
    __syncthreads();

    for (int c = blockIdx.x; c < N_NODES/4; c += gridDim.x){
        int n = c*4 + slot;
        int e0 = rs[n], e1 = rs[n+1];
        float a0 = 0.f, a1 = 0.f, a2 = 0.f, a3 = 0.f;
        int e = e0;
        for (; e + 3 < e1; e += 4){
            int c0 = col[e], c1 = col[e+1], c2 = col[e+2], c3 = col[e+3];
            a0 += xin[(long long)c0*FDIM + j];
            a1 += xin[(long long)c1*FDIM + j];
            a2 += xin[(long long)c2*FDIM + j];
            a3 += xin[(long long)c3*FDIM + j];
        }
        for (; e < e1; ++e) a0 += xin[(long long)col[e]*FDIM + j];
        float a = (a0+a1) + (a2+a3);
        float degf = (float)(e1 - e0);
        float rd = 1.f / fmaxf(degf, 1.f);
        // mean of affine(x) = (sc*sum + deg*sh)/deg ; deg==0 -> 0 (matches reference)
        rowA[slot][j] = AFFINE ? (a*scj + degf*shj)*rd : a*rd;
        float xv = xin[(long long)n*FDIM + j];
        rowX[slot][j] = AFFINE ? (xv*scj + shj) : xv;
        __syncthreads();
        float acc = blj;
        #pragma unroll 8
        for (int k = 0; k < FDIM; ++k)
            acc += rowA[slot][k]*sWl[k*FDIM + j] + rowX[slot][k]*sWr[k*FDIM + j];
        float h = leaky(acc);
        hout[(long long)n*FDIM + j] = h;
        bsumv += h; bsqv += h*h;
        __syncthreads();
    }

    red[t] = bsumv; __syncthreads();
    if (t < 64) atomicAdd(&bnsum[t], red[t]+red[t+64]+red[t+128]+red[t+192]);
    __syncthreads();
    red[t] = bsqv; __syncthreads();
    if (t < 64) atomicAdd(&bnsq[t],  red[t]+red[t+64]+red[t+128]+red[t+192]);
}

// ============ BN finalize ============
__global__ void k_bnfin(const float* __restrict__ sum, const float* __restrict__ sumsq,
                        const float* __restrict__ gamma, const float* __restrict__ beta,
                        float* __restrict__ scale, float* __restrict__ shift){
    int j = threadIdx.x;
    if (j < FDIM){
        float mu  = sum[j]   * (1.0f/N_NODES);
        float var = sumsq[j] * (1.0f/N_NODES) - mu*mu;
        float sc  = gamma[j] * rsqrtf(var + EPSV);
        scale[j] = sc;
        shift[j] = beta[j] - mu*sc;
    }
}

// ============ pooling: batch is sorted -> segmented reduction, no atomics ============
__global__ __launch_bounds__(256) void k_pool2(
    const float* __restrict__ h, const int* __restrict__ batch,
    const float* __restrict__ scale, const float* __restrict__ shift,
    float* __restrict__ pooled)
{
    __shared__ int seg[2];
    __shared__ float red[256];
    int g = blockIdx.x, t = threadIdx.x, j = t & 63, slot = t >> 6;
    if (t < 2){
        int target = g + t;
        int lo = 0, hi = N_NODES;
        while (lo < hi){ int mid = (lo+hi)>>1; if (batch[mid] < target) lo = mid+1; else hi = mid; }
        seg[t] = lo;
    }
    __syncthreads();
    int start = seg[0], end = seg[1];
    float acc = 0.f;
    for (int n = start + slot; n < end; n += 4)
        acc += h[(long long)n*FDIM + j];
    red[t] = acc; __syncthreads();
    if (t < 64){
        float s = red[t]+red[t+64]+red[t+128]+red[t+192];
        float c = fmaxf((float)(end - start), 1.f);
        pooled[g*FDIM + t] = (end > start) ? (s/c)*scale[t] + shift[t] : 0.f;
    }
}

// ============ final MLP: one block per graph ============
__global__ __launch_bounds__(256) void k_mlp(
    const float* __restrict__ pooled, const float* __restrict__ gf,
    const float* __restrict__ Wm0, const float* __restrict__ bm0,
    const float* __restrict__ Wm1, const float* __restrict__ bm1,
    const float* __restrict__ Wm2, const float* __restrict__ bm2,
    float* __restrict__ out)
{
    __shared__ float z[128];
    __shared__ float h1[256];
    __shared__ float h2[128];
    int g = blockIdx.x, t = threadIdx.x;
    if (t < 64)       z[t] = pooled[g*FDIM + t];
    else if (t < 128) z[t] = gf[g*FDIM + (t-64)];
    __syncthreads();
    float acc = bm0[t];
    #pragma unroll 8
    for (int k = 0; k < 128; ++k) acc += z[k]*Wm0[k*256 + t];
    h1[t] = leaky(acc);
    __syncthreads();
    if (t < 128){
        float a = bm1[t];
        #pragma unroll 8
        for (int k = 0; k < 256; ++k) a += h1[k]*Wm1[k*128 + t];
        h2[t] = leaky(a);
    }
    __syncthreads();
    if (t < 2){
        float a = bm2[t];
        for (int k = 0; k < 128; ++k) a += h2[k]*Wm2[k*2 + t];
        out[g*2 + t] = a;
    }
}

extern "C" void kernel_launch(void* const* d_in, const int* in_sizes, int n_in,
                              void* d_out, int out_size, void* d_ws, size_t ws_size,
                              hipStream_t stream) {
    const float* x     = (const float*)d_in[0];
    const int*   ei    = (const int*)d_in[1];      // [2, E]: src row then dst row
    const float* gf    = (const float*)d_in[2];
    const int*   batch = (const int*)d_in[3];
    const float* Wl0 = (const float*)d_in[4];
    const float* bl0 = (const float*)d_in[5];
    const float* Wr0 = (const float*)d_in[6];
    const float* g0  = (const float*)d_in[7];
    const float* b0  = (const float*)d_in[8];
    const float* Wl1 = (const float*)d_in[9];
    const float* bl1 = (const float*)d_in[10];
    const float* Wr1 = (const float*)d_in[11];
    const float* g1  = (const float*)d_in[12];
    const float* b1  = (const float*)d_in[13];
    const float* Wm0 = (const float*)d_in[14];
    const float* bm0 = (const float*)d_in[15];
    const float* Wm1 = (const float*)d_in[16];
    const float* bm1 = (const float*)d_in[17];
    const float* Wm2 = (const float*)d_in[18];
    const float* bm2 = (const float*)d_in[19];

    // ---- workspace layout ----
    int*   cnts_cur = (int*)d_ws;                       // [N] hist counts, then write cursors
    int*   rs       = cnts_cur + N_NODES;               // [N+1] CSR row starts
    int*   bsums    = rs + N_NODES + 1;                 // [128]
    int*   col      = bsums + 128;                      // [E] src per CSR slot
    float* bufA     = (float*)(col + N_EDGES);          // [N,64] h1
    float* bufB     = bufA + (size_t)N_NODES*FDIM;      // [N,64] h2
    float* bnsum    = bufB + (size_t)N_NODES*FDIM;      // [64]
    float* bnsq     = bnsum + 64;                       // [64]
    float* scale0   = bnsum + 128;
    float* shift0   = bnsum + 192;
    float* scale1   = bnsum + 256;
    float* shift1   = bnsum + 320;
    float* pooled   = bnsum + 384;                      // [128,64]

    const int* srcp = ei;
    const int* dstp = ei + N_EDGES;

    // ---- CSR build (once, shared by both layers) ----
    hipMemsetAsync(cnts_cur, 0, (size_t)N_NODES*sizeof(int), stream);
    k_hist<<<(N_EDGES+255)/256, 256, 0, stream>>>(dstp, cnts_cur);
    const int NBLK = (N_NODES + 1023)/1024;             // 98
    k_scanA<<<NBLK, 256, 0, stream>>>(cnts_cur, rs, bsums);
    k_scanB<<<1, 128, 0, stream>>>(bsums, NBLK);
    k_scanC<<<(N_NODES+255)/256, 256, 0, stream>>>(rs, bsums, cnts_cur);
    k_fill<<<(N_EDGES+255)/256, 256, 0, stream>>>(srcp, dstp, cnts_cur, col);

    // ---- layer 1 ----
    hipMemsetAsync(bnsum, 0, 128*sizeof(float), stream);
    k_hg<false><<<1024, 256, 0, stream>>>(x, rs, col, Wl0, bl0, Wr0, bufA,
                                          bnsum, bnsq, nullptr, nullptr);
    k_bnfin<<<1, 64, 0, stream>>>(bnsum, bnsq, g0, b0, scale0, shift0);

    // ---- layer 2 ----
    hipMemsetAsync(bnsum, 0, 128*sizeof(float), stream);
    k_hg<true><<<1024, 256, 0, stream>>>(bufA, rs, col, Wl1, bl1, Wr1, bufB,
                                         bnsum, bnsq, scale0, shift0);
    k_bnfin<<<1, 64, 0, stream>>>(bnsum, bnsq, g1, b1, scale1, shift1);

    // ---- pooling + MLP ----
    k_pool2<<<N_GRAPHS, 256, 0, stream>>>(bufB, batch, scale1, shift1, pooled);
    k_mlp<<<N_GRAPHS, 256, 0, stream>>>(pooled, gf, Wm0, bm0, Wm1, bm1, Wm2, bm2, (float*)d_out);
}

// Round 3
// 597.177 us; speedup vs baseline: 2.6365x; 1.0824x over previous
//
#include <hip/hip_runtime.h>

#define N_NODES 100000
#define N_EDGES 1600000
#define N_GRAPHS 128
#define FDIM 64
#define EPSV 1e-5f
#define NEG 0.01f

__device__ __forceinline__ float leaky(float x){ return x >= 0.f ? x : NEG*x; }
__device__ __forceinline__ float bcastf(float v, int k){
    return __uint_as_float((unsigned)__builtin_amdgcn_readlane(__float_as_uint(v), k));
}

// ================= CSR build =================
__global__ void k_hist(const int* __restrict__ dst, int* __restrict__ cnts){
    int e = blockIdx.x*256 + threadIdx.x;
    if (e < N_EDGES) atomicAdd(&cnts[dst[e]], 1);
}

__global__ __launch_bounds__(256) void k_scanA(const int* __restrict__ cnts,
                                               int* __restrict__ rs, int* __restrict__ bsum){
    __shared__ int lds[256];
    int b = blockIdx.x, t = threadIdx.x;
    int base = b*1024 + t*4;
    int v0=0,v1=0,v2=0,v3=0;
    if (base+0 < N_NODES) v0 = cnts[base+0];
    if (base+1 < N_NODES) v1 = cnts[base+1];
    if (base+2 < N_NODES) v2 = cnts[base+2];
    if (base+3 < N_NODES) v3 = cnts[base+3];
    lds[t] = v0+v1+v2+v3; __syncthreads();
    for (int off=1; off<256; off<<=1){
        int add = (t>=off) ? lds[t-off] : 0; __syncthreads();
        lds[t] += add; __syncthreads();
    }
    int excl = (t>0) ? lds[t-1] : 0;
    if (base+0 < N_NODES) rs[base+0] = excl;
    if (base+1 < N_NODES) rs[base+1] = excl+v0;
    if (base+2 < N_NODES) rs[base+2] = excl+v0+v1;
    if (base+3 < N_NODES) rs[base+3] = excl+v0+v1+v2;
    if (t == 255) bsum[b] = lds[255];
}

__global__ void k_scanB(int* __restrict__ bsum, int nblk){
    __shared__ int lds[128];
    int t = threadIdx.x;
    lds[t] = (t < nblk) ? bsum[t] : 0; __syncthreads();
    for (int off=1; off<128; off<<=1){
        int add = (t>=off) ? lds[t-off] : 0; __syncthreads();
        lds[t] += add; __syncthreads();
    }
    if (t < nblk) bsum[t] = (t>0) ? lds[t-1] : 0;
}

__global__ void k_scanC(int* __restrict__ rs, const int* __restrict__ bsum, int* __restrict__ cur){
    int i = blockIdx.x*256 + threadIdx.x;
    if (i < N_NODES){
        int v = rs[i] + bsum[i>>10];
        rs[i] = v; cur[i] = v;
    }
    if (i == 0) rs[N_NODES] = N_EDGES;
}

__global__ void k_fill(const int* __restrict__ src, const int* __restrict__ dst,
                       int* __restrict__ cur, int* __restrict__ col){
    int e = blockIdx.x*256 + threadIdx.x;
    if (e < N_EDGES){
        int p = atomicAdd(&cur[dst[e]], 1);
        col[p] = src[e];
    }
}

// ============ pure gather-mean: wave per node, 16 lanes x float4, 4 edges/instr ============
__global__ __launch_bounds__(256) void k_agg(
    const float* __restrict__ xin, const int* __restrict__ rs, const int* __restrict__ col,
    float* __restrict__ agg)
{
    int t = threadIdx.x;
    int lane = t & 63;
    int sub = lane >> 4;          // edge slot 0..3
    int q   = lane & 15;          // feature quad
    int wid = (blockIdx.x << 2) + (t >> 6);
    const int nw = gridDim.x << 2;
    for (int n = wid; n < N_NODES; n += nw){
        int e0 = __builtin_amdgcn_readfirstlane(rs[n]);
        int e1 = __builtin_amdgcn_readfirstlane(rs[n+1]);
        float ax=0.f, ay=0.f, az=0.f, aw=0.f;
        for (int e = e0; e < e1; e += 8){
            int i0 = e + sub, i1 = e + 4 + sub;
            if (i0 < e1){
                const float4* row = (const float4*)(xin + ((size_t)col[i0] << 6));
                float4 v = row[q];
                ax += v.x; ay += v.y; az += v.z; aw += v.w;
            }
            if (i1 < e1){
                const float4* row = (const float4*)(xin + ((size_t)col[i1] << 6));
                float4 v = row[q];
                ax += v.x; ay += v.y; az += v.z; aw += v.w;
            }
        }
        ax += __shfl_xor(ax, 16, 64); ay += __shfl_xor(ay, 16, 64);
        az += __shfl_xor(az, 16, 64); aw += __shfl_xor(aw, 16, 64);
        ax += __shfl_xor(ax, 32, 64); ay += __shfl_xor(ay, 32, 64);
        az += __shfl_xor(az, 32, 64); aw += __shfl_xor(aw, 32, 64);
        if (sub == 0){
            float rd = 1.f / fmaxf((float)(e1 - e0), 1.f);
            float4 o = make_float4(ax*rd, ay*rd, az*rd, aw*rd);
            ((float4*)(agg + ((size_t)n << 6)))[q] = o;
        }
    }
}

// ============ streaming dual-GEMM + leaky + BN partials; affine folded into weights ============
// aggh: agg in, h out (in-place). xin: root-branch input (raw h of prev layer or x).
template<bool AFF>
__global__ __launch_bounds__(256) void k_gemm(
    float* aggh, const float* __restrict__ xin,
    const int* __restrict__ rs,
    const float* __restrict__ Wl, const float* __restrict__ bl,
    const float* __restrict__ Wr,
    const float* __restrict__ scale, const float* __restrict__ shift,
    float* __restrict__ bnsum, float* __restrict__ bnsq)
{
    __shared__ float sWl[4096];
    __shared__ float sWr[4096];
    __shared__ float red[256];
    int t = threadIdx.x;
    int lane = t & 63;
    for (int i = t; i < 4096; i += 256){
        float s = AFF ? scale[i >> 6] : 1.f;
        sWl[i] = Wl[i] * s;
        sWr[i] = Wr[i] * s;
    }
    float bb = bl[lane], bd = 0.f;
    if (AFF){
        #pragma unroll 8
        for (int k = 0; k < 64; ++k){
            float sh = shift[k];
            bb += sh * Wr[(k<<6) + lane];
            bd += sh * Wl[(k<<6) + lane];
        }
    }
    __syncthreads();
    float bs = 0.f, bq = 0.f;
    int wid = (blockIdx.x << 2) + (t >> 6);
    int nw = gridDim.x << 2;
    for (int c = wid; c < N_NODES/4; c += nw){
        int n0 = c << 2;
        float aA[4], aX[4], acc[4];
        #pragma unroll
        for (int m = 0; m < 4; ++m){
            aA[m] = aggh[((size_t)(n0+m) << 6) + lane];
            aX[m] = xin[((size_t)(n0+m) << 6) + lane];
            if (AFF){
                int d = rs[n0+m+1] - rs[n0+m];
                acc[m] = bb + (d > 0 ? bd : 0.f);
            } else acc[m] = bb;
        }
        #pragma unroll 8
        for (int k = 0; k < 64; ++k){
            float wl = sWl[(k<<6) + lane];
            float wr = sWr[(k<<6) + lane];
            #pragma unroll
            for (int m = 0; m < 4; ++m)
                acc[m] += bcastf(aA[m], k)*wl + bcastf(aX[m], k)*wr;
        }
        #pragma unroll
        for (int m = 0; m < 4; ++m){
            float h = leaky(acc[m]);
            aggh[((size_t)(n0+m) << 6) + lane] = h;
            bs += h; bq += h*h;
        }
    }
    red[t] = bs; __syncthreads();
    if (t < 64) atomicAdd(&bnsum[t], red[t]+red[t+64]+red[t+128]+red[t+192]);
    __syncthreads();
    red[t] = bq; __syncthreads();
    if (t < 64) atomicAdd(&bnsq[t],  red[t]+red[t+64]+red[t+128]+red[t+192]);
}

// ============ BN finalize ============
__global__ void k_bnfin(const float* __restrict__ sum, const float* __restrict__ sumsq,
                        const float* __restrict__ gamma, const float* __restrict__ beta,
                        float* __restrict__ scale, float* __restrict__ shift){
    int j = threadIdx.x;
    if (j < FDIM){
        float mu  = sum[j]   * (1.0f/N_NODES);
        float var = sumsq[j] * (1.0f/N_NODES) - mu*mu;
        float sc  = gamma[j] * rsqrtf(var + EPSV);
        scale[j] = sc;
        shift[j] = beta[j] - mu*sc;
    }
}

// ============ pooling: sorted batch -> segmented reduction ============
__global__ __launch_bounds__(256) void k_pool2(
    const float* __restrict__ h, const int* __restrict__ batch,
    const float* __restrict__ scale, const float* __restrict__ shift,
    float* __restrict__ pooled)
{
    __shared__ int seg[2];
    __shared__ float red[256];
    int g = blockIdx.x, t = threadIdx.x, j = t & 63, slot = t >> 6;
    if (t < 2){
        int target = g + t;
        int lo = 0, hi = N_NODES;
        while (lo < hi){ int mid = (lo+hi)>>1; if (batch[mid] < target) lo = mid+1; else hi = mid; }
        seg[t] = lo;
    }
    __syncthreads();
    int start = seg[0], end = seg[1];
    float acc = 0.f;
    for (int n = start + slot; n < end; n += 4)
        acc += h[(long long)n*FDIM + j];
    red[t] = acc; __syncthreads();
    if (t < 64){
        float s = red[t]+red[t+64]+red[t+128]+red[t+192];
        float c = fmaxf((float)(end - start), 1.f);
        pooled[g*FDIM + t] = (end > start) ? (s/c)*scale[t] + shift[t] : 0.f;
    }
}

// ============ final MLP ============
__global__ __launch_bounds__(256) void k_mlp(
    const float* __restrict__ pooled, const float* __restrict__ gf,
    const float* __restrict__ Wm0, const float* __restrict__ bm0,
    const float* __restrict__ Wm1, const float* __restrict__ bm1,
    const float* __restrict__ Wm2, const float* __restrict__ bm2,
    float* __restrict__ out)
{
    __shared__ float z[128];
    __shared__ float h1[256];
    __shared__ float h2[128];
    int g = blockIdx.x, t = threadIdx.x;
    if (t < 64)       z[t] = pooled[g*FDIM + t];
    else if (t < 128) z[t] = gf[g*FDIM + (t-64)];
    __syncthreads();
    float acc = bm0[t];
    #pragma unroll 8
    for (int k = 0; k < 128; ++k) acc += z[k]*Wm0[k*256 + t];
    h1[t] = leaky(acc);
    __syncthreads();
    if (t < 128){
        float a = bm1[t];
        #pragma unroll 8
        for (int k = 0; k < 256; ++k) a += h1[k]*Wm1[k*128 + t];
        h2[t] = leaky(a);
    }
    __syncthreads();
    if (t < 2){
        float a = bm2[t];
        for (int k = 0; k < 128; ++k) a += h2[k]*Wm2[k*2 + t];
        out[g*2 + t] = a;
    }
}

extern "C" void kernel_launch(void* const* d_in, const int* in_sizes, int n_in,
                              void* d_out, int out_size, void* d_ws, size_t ws_size,
                              hipStream_t stream) {
    const float* x     = (const float*)d_in[0];
    const int*   ei    = (const int*)d_in[1];
    const float* gf    = (const float*)d_in[2];
    const int*   batch = (const int*)d_in[3];
    const float* Wl0 = (const float*)d_in[4];
    const float* bl0 = (const float*)d_in[5];
    const float* Wr0 = (const float*)d_in[6];
    const float* g0  = (const float*)d_in[7];
    const float* b0  = (const float*)d_in[8];
    const float* Wl1 = (const float*)d_in[9];
    const float* bl1 = (const float*)d_in[10];
    const float* Wr1 = (const float*)d_in[11];
    const float* g1  = (const float*)d_in[12];
    const float* b1  = (const float*)d_in[13];
    const float* Wm0 = (const float*)d_in[14];
    const float* bm0 = (const float*)d_in[15];
    const float* Wm1 = (const float*)d_in[16];
    const float* bm1 = (const float*)d_in[17];
    const float* Wm2 = (const float*)d_in[18];
    const float* bm2 = (const float*)d_in[19];

    // ---- workspace ----
    int*   cnts_cur = (int*)d_ws;                       // [N]
    int*   rs       = cnts_cur + N_NODES;               // [N+1]
    int*   bsums    = rs + N_NODES + 1;                 // [128]
    int*   col      = bsums + 128;                      // [E]
    float* bufA     = (float*)(col + N_EDGES);          // [N,64] agg1 -> h1 (in-place)
    float* bufB     = bufA + (size_t)N_NODES*FDIM;      // [N,64] agg2 -> h2 (in-place)
    float* bnsum    = bufB + (size_t)N_NODES*FDIM;      // [64]
    float* bnsq     = bnsum + 64;
    float* scale0   = bnsum + 128;
    float* shift0   = bnsum + 192;
    float* scale1   = bnsum + 256;
    float* shift1   = bnsum + 320;
    float* pooled   = bnsum + 384;                      // [128,64]

    const int* srcp = ei;
    const int* dstp = ei + N_EDGES;

    // ---- CSR build ----
    hipMemsetAsync(cnts_cur, 0, (size_t)N_NODES*sizeof(int), stream);
    k_hist<<<(N_EDGES+255)/256, 256, 0, stream>>>(dstp, cnts_cur);
    const int NBLK = (N_NODES + 1023)/1024;             // 98
    k_scanA<<<NBLK, 256, 0, stream>>>(cnts_cur, rs, bsums);
    k_scanB<<<1, 128, 0, stream>>>(bsums, NBLK);
    k_scanC<<<(N_NODES+255)/256, 256, 0, stream>>>(rs, bsums, cnts_cur);
    k_fill<<<(N_EDGES+255)/256, 256, 0, stream>>>(srcp, dstp, cnts_cur, col);

    // ---- layer 1 ----
    hipMemsetAsync(bnsum, 0, 128*sizeof(float), stream);
    k_agg<<<2048, 256, 0, stream>>>(x, rs, col, bufA);
    k_gemm<false><<<1024, 256, 0, stream>>>(bufA, x, rs, Wl0, bl0, Wr0,
                                            nullptr, nullptr, bnsum, bnsq);
    k_bnfin<<<1, 64, 0, stream>>>(bnsum, bnsq, g0, b0, scale0, shift0);

    // ---- layer 2 ----
    hipMemsetAsync(bnsum, 0, 128*sizeof(float), stream);
    k_agg<<<2048, 256, 0, stream>>>(bufA, rs, col, bufB);
    k_gemm<true><<<1024, 256, 0, stream>>>(bufB, bufA, rs, Wl1, bl1, Wr1,
                                           scale0, shift0, bnsum, bnsq);
    k_bnfin<<<1, 64, 0, stream>>>(bnsum, bnsq, g1, b1, scale1, shift1);

    // ---- pooling + MLP ----
    k_pool2<<<N_GRAPHS, 256, 0, stream>>>(bufB, batch, scale1, shift1, pooled);
    k_mlp<<<N_GRAPHS, 256, 0, stream>>>(pooled, gf, Wm0, bm0, Wm1, bm1, Wm2, bm2, (float*)d_out);
}